// Round 1
// baseline (356.794 us; speedup 1.0000x reference)
//
#include <hip/hip_runtime.h>
#include <hip/hip_bf16.h>

// TreeRNN: K=8, DEPTH=7, N=299593, V=32000, X=H=O=128.
// Strategy: bf16 MFMA (16x16x32) with fp32 accumulate. Per level (processed
// leaves->root), one fused kernel: gather-embed GEMM (W_in) + child-sum GEMM
// (U) + tanh + out GEMM (W_out). Weights pre-swizzled into MFMA B-fragment
// order in ws by a prep kernel (32KB each -> L1-resident). h stored bf16 in ws.

typedef __bf16 bf16x8 __attribute__((ext_vector_type(8)));
typedef float f32x4 __attribute__((ext_vector_type(4)));
typedef unsigned short ushort8 __attribute__((ext_vector_type(8)));

#define NNODES 299593

static __device__ __forceinline__ unsigned short f2bf(float f) {
  union { float f; unsigned int u; } v; v.f = f;
  unsigned int u = v.u;
  u += 0x7fff + ((u >> 16) & 1);   // RNE
  return (unsigned short)(u >> 16);
}
static __device__ __forceinline__ float bf2f(unsigned short h) {
  union { unsigned int u; float f; } v; v.u = ((unsigned int)h) << 16;
  return v.f;
}

// Swizzle W (128x128 row-major fp32) into B-fragment order for
// v_mfma_f32_16x16x32_bf16: frag index f = ((kt*8+nt)*64 + lane)*8 + j
// holds W[kt*32 + (lane>>4)*8 + j][nt*16 + (lane&15)].
__global__ void prep_weights(const float* __restrict__ W_in,
                             const float* __restrict__ U,
                             const float* __restrict__ W_out,
                             unsigned short* __restrict__ w_sw) {
  int f = blockIdx.x * 256 + threadIdx.x;   // 0..49151
  int m = f >> 14;
  int r = f & 16383;
  int j = r & 7;
  int lane = (r >> 3) & 63;
  int nt = (r >> 9) & 7;
  int kt = (r >> 12) & 3;
  int k = kt * 32 + ((lane >> 4) * 8) + j;
  int n = nt * 16 + (lane & 15);
  const float* W = (m == 0) ? W_in : (m == 1) ? U : W_out;
  w_sw[f] = f2bf(W[k * 128 + n]);
}

// One wave computes a 16x128 C tile: A rows m = lane&15 from LDS
// (row stride 136 ushorts: +8 pad -> 2-way bank alias only, free),
// B fragments from pre-swizzled global (L1-hit broadcast across waves).
static __device__ __forceinline__ void gemm16(f32x4 acc[8],
    const unsigned short* a_base, const unsigned short* b_sw, int lane) {
  const int coll = lane & 15;
  const int quad = lane >> 4;
#pragma unroll
  for (int kt = 0; kt < 4; ++kt) {
    bf16x8 a = *(const bf16x8*)(a_base + coll * 136 + kt * 32 + quad * 8);
#pragma unroll
    for (int nt = 0; nt < 8; ++nt) {
      bf16x8 b = *(const bf16x8*)(b_sw + (((kt * 8 + nt) * 64 + lane) * 8));
      acc[nt] = __builtin_amdgcn_mfma_f32_16x16x32_bf16(a, b, acc[nt], 0, 0, 0);
    }
  }
}

template <bool LEAF>
__global__ __launch_bounds__(256) void level_kernel(
    const int* __restrict__ x, const int* __restrict__ mask,
    const float* __restrict__ emb, const float* __restrict__ b_in,
    const float* __restrict__ b_out, const unsigned short* __restrict__ w_sw,
    unsigned short* __restrict__ h, float* __restrict__ out, int s, int e) {
  __shared__ __align__(16) unsigned short Abuf[64][136];
  const int tid = threadIdx.x;
  const int lane = tid & 63;
  const int wave = tid >> 6;
  const int row0 = s + blockIdx.x * 64;

  // ---- phase 1: stage masked embeds (bf16) ----
  {
    const int r = tid >> 2;       // 0..63 (wave-local rows: wave w stages 16w..16w+15)
    const int cg = tid & 3;       // 32-col group
    const int grow = row0 + r;
    const int valid = (grow < e);
    const int m = valid ? mask[grow] : 0;
    const int idx = valid ? x[grow] * m : 0;
    const float fm = (float)m;
    const float* erow = emb + (size_t)idx * 128 + cg * 32;
#pragma unroll
    for (int b = 0; b < 4; ++b) {
      f32x4 v0 = *(const f32x4*)(erow + b * 8);
      f32x4 v1 = *(const f32x4*)(erow + b * 8 + 4);
      ushort8 w;
#pragma unroll
      for (int q = 0; q < 4; ++q) {
        w[q] = f2bf(v0[q] * fm);
        w[q + 4] = f2bf(v1[q] * fm);
      }
      *(ushort8*)&Abuf[r][cg * 32 + b * 8] = w;
    }
  }
  __syncthreads();

  f32x4 acc[8];
#pragma unroll
  for (int nt = 0; nt < 8; ++nt) acc[nt] = (f32x4){0.f, 0.f, 0.f, 0.f};
  gemm16(acc, &Abuf[wave * 16][0], w_sw, lane);           // emb @ W_in

  if (!LEAF) {
    __syncthreads();
    // ---- phase 2: stage sum of 8 contiguous children h rows ----
    {
      const int r = tid >> 2;
      const int cg = tid & 3;
      const int grow = row0 + r;
      float sums[32];
#pragma unroll
      for (int q = 0; q < 32; ++q) sums[q] = 0.f;
      if (grow < e) {
        const unsigned short* hp = h + ((size_t)grow * 8 + 1) * 128 + cg * 32;
#pragma unroll
        for (int j = 0; j < 8; ++j) {
#pragma unroll
          for (int b = 0; b < 4; ++b) {
            ushort8 hv = *(const ushort8*)(hp + j * 128 + b * 8);
#pragma unroll
            for (int q = 0; q < 8; ++q) sums[b * 8 + q] += bf2f(hv[q]);
          }
        }
      }
#pragma unroll
      for (int b = 0; b < 4; ++b) {
        ushort8 w;
#pragma unroll
        for (int q = 0; q < 8; ++q) w[q] = f2bf(sums[b * 8 + q]);
        *(ushort8*)&Abuf[r][cg * 32 + b * 8] = w;
      }
    }
    __syncthreads();
    gemm16(acc, &Abuf[wave * 16][0], w_sw + 16384, lane);  // (sum ch) @ U
  }

  __syncthreads();

  // ---- epilogue 1: + m*b_in, tanh; h -> LDS (A for out-GEMM) + global bf16
  const int coll = lane & 15;
  const int quad = lane >> 4;
#pragma unroll
  for (int r2 = 0; r2 < 4; ++r2) {
    const int rowl = wave * 16 + quad * 4 + r2;   // C layout: row=(lane>>4)*4+reg
    const int grow = row0 + rowl;
    const int valid = (grow < e);
    const float mval = valid ? (float)mask[grow] : 0.f;
#pragma unroll
    for (int nt = 0; nt < 8; ++nt) {
      const int col = nt * 16 + coll;
      float t = acc[nt][r2] + mval * b_in[col];
      float hv = tanhf(t);
      unsigned short hb = f2bf(hv);
      Abuf[rowl][col] = hb;
      if (valid) h[(size_t)grow * 128 + col] = hb;
    }
  }
  __syncthreads();

  // ---- GEMM 2: out = h @ W_out + b_out (fp32 store) ----
  f32x4 oacc[8];
#pragma unroll
  for (int nt = 0; nt < 8; ++nt) oacc[nt] = (f32x4){0.f, 0.f, 0.f, 0.f};
  gemm16(oacc, &Abuf[wave * 16][0], w_sw + 32768, lane);

#pragma unroll
  for (int r2 = 0; r2 < 4; ++r2) {
    const int rowl = wave * 16 + quad * 4 + r2;
    const int grow = row0 + rowl;
    if (grow < e) {
#pragma unroll
      for (int nt = 0; nt < 8; ++nt) {
        const int col = nt * 16 + coll;
        out[(size_t)grow * 128 + col] = oacc[nt][r2] + b_out[col];
      }
    }
  }
}

extern "C" void kernel_launch(void* const* d_in, const int* in_sizes, int n_in,
                              void* d_out, int out_size, void* d_ws,
                              size_t ws_size, hipStream_t stream) {
  const int* x = (const int*)d_in[0];
  const int* mask = (const int*)d_in[1];
  // d_in[2] = children: implied by tree structure (child rows = i*8+1..i*8+8)
  const float* emb = (const float*)d_in[3];
  const float* W_in = (const float*)d_in[4];
  const float* b_in = (const float*)d_in[5];
  const float* U = (const float*)d_in[6];
  const float* W_out = (const float*)d_in[7];
  const float* b_out = (const float*)d_in[8];
  float* out = (float*)d_out;

  // ws layout: h bf16 [NNODES*128 ushort] | swizzled weights [3*16384 ushort]
  unsigned short* h = (unsigned short*)d_ws;
  unsigned short* w_sw = h + (size_t)NNODES * 128;

  prep_weights<<<192, 256, 0, stream>>>(W_in, U, W_out, w_sw);

  static const int offs[8] = {0, 1, 9, 73, 585, 4681, 37449, 299593};
  {  // leaf level l=6
    int s = offs[6], e = offs[7];
    level_kernel<true><<<(e - s + 63) / 64, 256, 0, stream>>>(
        x, mask, emb, b_in, b_out, w_sw, h, out, s, e);
  }
  for (int l = 5; l >= 0; --l) {
    int s = offs[l], e = offs[l + 1];
    level_kernel<false><<<(e - s + 63) / 64, 256, 0, stream>>>(
        x, mask, emb, b_in, b_out, w_sw, h, out, s, e);
  }
}

// Round 3
// 314.168 us; speedup vs baseline: 1.1357x; 1.1357x over previous
//
#include <hip/hip_runtime.h>
#include <hip/hip_bf16.h>

// TreeRNN: K=8, DEPTH=7, N=299593, V=32000, X=H=O=128.
// bf16 MFMA 16x16x32, fp32 accumulate. Per level: fused gather-embed GEMM
// (W_in) + child-sum GEMM (U) + fast-tanh + out GEMM (W_out).
// All LDS phases are wave-private (each wave stages/consumes its own 16 rows)
// -> NO __syncthreads in the level path (CDNA DS pipe is in-order per wave;
// wave_barrier() pins compiler ordering at zero cost).
// Levels 2..0 (73 rows) merged into one single-block tail kernel.

typedef __bf16 bf16x8 __attribute__((ext_vector_type(8)));
typedef float f32x4 __attribute__((ext_vector_type(4)));
typedef float f32x2 __attribute__((ext_vector_type(2)));
typedef unsigned short ushort8 __attribute__((ext_vector_type(8)));

#define NNODES 299593

static __device__ __forceinline__ unsigned short f2bf(float f) {
  union { float f; unsigned int u; } v; v.f = f;
  unsigned int u = v.u;
  u += 0x7fff + ((u >> 16) & 1);   // RNE
  return (unsigned short)(u >> 16);
}

// pack 2 floats -> 2 bf16 in one dword (a -> low, b -> high)
static __device__ __forceinline__ unsigned int pk2bf(float a, float b) {
#if __has_builtin(__builtin_amdgcn_cvt_pk_bf16_f32)
  typedef __bf16 bf16x2 __attribute__((ext_vector_type(2)));
  union { bf16x2 v; unsigned int u; } c;
  c.v = __builtin_amdgcn_cvt_pk_bf16_f32(a, b);
  return c.u;
#else
  return (unsigned int)f2bf(a) | ((unsigned int)f2bf(b) << 16);
#endif
}

// tanh(x) = 1 - 2/(1+e^{2x});  ~5 VALU ops vs ~20 for tanhf.
// abs error ~1e-6 << bf16 storage quantization already in the pipeline.
static __device__ __forceinline__ float fast_tanh(float x) {
  float y = x * 2.885390081777927f;  // 2*log2(e)
#if __has_builtin(__builtin_amdgcn_exp2f)
  float e = __builtin_amdgcn_exp2f(y);
#else
  float e = __builtin_exp2f(y);
#endif
#if __has_builtin(__builtin_amdgcn_rcpf)
  float r = __builtin_amdgcn_rcpf(e + 1.0f);
#else
  float r = 1.0f / (e + 1.0f);
#endif
  return __builtin_fmaf(-2.0f, r, 1.0f);
}

// Swizzle W (128x128 row-major fp32) into B-fragment order for
// v_mfma_f32_16x16x32_bf16: frag f = ((kt*8+nt)*64 + lane)*8 + j
// holds W[kt*32 + (lane>>4)*8 + j][nt*16 + (lane&15)].
__global__ void prep_weights(const float* __restrict__ W_in,
                             const float* __restrict__ U,
                             const float* __restrict__ W_out,
                             unsigned short* __restrict__ w_sw) {
  int f = blockIdx.x * 256 + threadIdx.x;   // 0..49151
  int m = f >> 14;
  int r = f & 16383;
  int j = r & 7;
  int lane = (r >> 3) & 63;
  int nt = (r >> 9) & 7;
  int kt = (r >> 12) & 3;
  int k = kt * 32 + ((lane >> 4) * 8) + j;
  int n = nt * 16 + (lane & 15);
  const float* W = (m == 0) ? W_in : (m == 1) ? U : W_out;
  w_sw[f] = f2bf(W[k * 128 + n]);
}

// One wave computes a 16x128 C tile. A rows (m = lane&15) from wave-private
// LDS region (row stride 136 ushorts), B fragments from pre-swizzled global
// (L1-resident, 32 KB/matrix).
static __device__ __forceinline__ void gemm16(f32x4 acc[8],
    const unsigned short* a_base, const unsigned short* b_sw, int lane) {
  const int coll = lane & 15;
  const int quad = lane >> 4;
#pragma unroll
  for (int kt = 0; kt < 4; ++kt) {
    bf16x8 a = *(const bf16x8*)(a_base + coll * 136 + kt * 32 + quad * 8);
#pragma unroll
    for (int nt = 0; nt < 8; ++nt) {
      bf16x8 b = *(const bf16x8*)(b_sw + (((kt * 8 + nt) * 64 + lane) * 8));
      acc[nt] = __builtin_amdgcn_mfma_f32_16x16x32_bf16(a, b, acc[nt], 0, 0, 0);
    }
  }
}

template <bool LEAF>
static __device__ __forceinline__ void tile_body(
    const int* __restrict__ x, const int* __restrict__ mask,
    const float* __restrict__ emb, const float* __restrict__ b_in,
    const float* __restrict__ b_out, const unsigned short* __restrict__ w_sw,
    unsigned short* __restrict__ h, float* __restrict__ out,
    int e, int row0, unsigned short (*Abuf)[136], int tid) {
  const int lane = tid & 63;
  const int wave = tid >> 6;

  // ---- phase 1: stage masked embeds (bf16) — wave-private rows ----
  {
    const int r = tid >> 2;       // wave w stages rows 16w..16w+15
    const int cg = tid & 3;       // 32-col group
    const int grow = row0 + r;
    const int valid = (grow < e);
    const int m = valid ? mask[grow] : 0;
    const int idx = valid ? x[grow] * m : 0;
    const float fm = (float)m;
    const float* erow = emb + (size_t)idx * 128 + cg * 32;
#pragma unroll
    for (int b = 0; b < 4; ++b) {
      f32x4 v0 = *(const f32x4*)(erow + b * 8);
      f32x4 v1 = *(const f32x4*)(erow + b * 8 + 4);
      union { ushort8 s; unsigned int u[4]; } w;
      w.u[0] = pk2bf(v0[0] * fm, v0[1] * fm);
      w.u[1] = pk2bf(v0[2] * fm, v0[3] * fm);
      w.u[2] = pk2bf(v1[0] * fm, v1[1] * fm);
      w.u[3] = pk2bf(v1[2] * fm, v1[3] * fm);
      *(ushort8*)&Abuf[r][cg * 32 + b * 8] = w.s;
    }
  }
  __builtin_amdgcn_wave_barrier();

  f32x4 acc[8];
#pragma unroll
  for (int nt = 0; nt < 8; ++nt) acc[nt] = (f32x4){0.f, 0.f, 0.f, 0.f};
  gemm16(acc, &Abuf[wave * 16][0], w_sw, lane);            // emb @ W_in

  if (!LEAF) {
    // ---- phase 2: stage sum of 8 contiguous children h rows (fp32 acc) ----
    const int r = tid >> 2;
    const int cg = tid & 3;
    const int grow = row0 + r;
    f32x2 sums[16];   // col pairs (b*16+2q, b*16+2q+1) -> v_pk_add_f32
#pragma unroll
    for (int q = 0; q < 16; ++q) sums[q] = (f32x2){0.f, 0.f};
    if (grow < e) {
      const unsigned short* hp = h + ((size_t)grow * 8 + 1) * 128 + cg * 32;
#pragma unroll
      for (int j = 0; j < 8; ++j) {
#pragma unroll
        for (int b = 0; b < 2; ++b) {
          union { ushort8 s; unsigned int u[4]; } hv;
          hv.s = *(const ushort8*)(hp + j * 128 + b * 16);
#pragma unroll
          for (int q = 0; q < 4; ++q) {
            union { unsigned int u; float f; } lo, hi;
            lo.u = hv.u[q] << 16;
            hi.u = hv.u[q] & 0xffff0000u;
            sums[b * 8 + q] += (f32x2){lo.f, hi.f};
          }
          hv.s = *(const ushort8*)(hp + j * 128 + b * 16 + 8);
#pragma unroll
          for (int q = 0; q < 4; ++q) {
            union { unsigned int u; float f; } lo, hi;
            lo.u = hv.u[q] << 16;
            hi.u = hv.u[q] & 0xffff0000u;
            sums[b * 8 + 4 + q] += (f32x2){lo.f, hi.f};
          }
        }
      }
    }
    // writeback: sums[b*8+q] = cols cg*32 + b*16 + (2q,2q+1)
    // (round-2 bug was here: w0 landed at cg*32+b*32, stomping neighbor cg)
#pragma unroll
    for (int b = 0; b < 2; ++b) {
      union { ushort8 s; unsigned int u[4]; } w0, w1;
#pragma unroll
      for (int q = 0; q < 4; ++q) {
        w0.u[q] = pk2bf(sums[b * 8 + q][0], sums[b * 8 + q][1]);
        w1.u[q] = pk2bf(sums[b * 8 + 4 + q][0], sums[b * 8 + 4 + q][1]);
      }
      *(ushort8*)&Abuf[r][cg * 32 + b * 16] = w0.s;
      *(ushort8*)&Abuf[r][cg * 32 + b * 16 + 8] = w1.s;
    }
    __builtin_amdgcn_wave_barrier();
    gemm16(acc, &Abuf[wave * 16][0], w_sw + 16384, lane);  // (sum ch) @ U
  }

  // ---- epilogue 1: + m*b_in, fast tanh; h -> LDS (wave-private) ----
  const int coll = lane & 15;
  const int quad = lane >> 4;
  float binv[8];
#pragma unroll
  for (int nt = 0; nt < 8; ++nt) binv[nt] = b_in[nt * 16 + coll];
#pragma unroll
  for (int r2 = 0; r2 < 4; ++r2) {
    const int rowl = wave * 16 + quad * 4 + r2;   // C layout: row=quad*4+reg
    const int grow = row0 + rowl;
    const float mval = (grow < e) ? (float)mask[grow] : 0.f;
#pragma unroll
    for (int nt = 0; nt < 8; ++nt) {
      float t = acc[nt][r2] + mval * binv[nt];
      Abuf[rowl][nt * 16 + coll] = f2bf(fast_tanh(t));
    }
  }
  __builtin_amdgcn_wave_barrier();

  // ---- store h (bf16) vectorized from LDS: 64B-coalesced dwordx4 ----
  {
    const int sr = wave * 16 + (lane >> 2);
    const int sc = (lane & 3) * 8;
    const int grow = row0 + sr;
    if (grow < e) {
      unsigned short* hp = h + (size_t)grow * 128;
#pragma unroll
      for (int i = 0; i < 4; ++i)
        *(ushort8*)(hp + sc + i * 32) = *(const ushort8*)&Abuf[sr][sc + i * 32];
    }
  }

  // ---- GEMM 2: out = h @ W_out + b_out (fp32) ----
  f32x4 oacc[8];
#pragma unroll
  for (int nt = 0; nt < 8; ++nt) oacc[nt] = (f32x4){0.f, 0.f, 0.f, 0.f};
  gemm16(oacc, &Abuf[wave * 16][0], w_sw + 32768, lane);

  float boutv[8];
#pragma unroll
  for (int nt = 0; nt < 8; ++nt) boutv[nt] = b_out[nt * 16 + coll];
#pragma unroll
  for (int r2 = 0; r2 < 4; ++r2) {
    const int rowl = wave * 16 + quad * 4 + r2;
    const int grow = row0 + rowl;
    if (grow < e) {
#pragma unroll
      for (int nt = 0; nt < 8; ++nt)
        out[(size_t)grow * 128 + nt * 16 + coll] = oacc[nt][r2] + boutv[nt];
    }
  }
}

template <bool LEAF>
__global__ __launch_bounds__(256) void level_kernel(
    const int* __restrict__ x, const int* __restrict__ mask,
    const float* __restrict__ emb, const float* __restrict__ b_in,
    const float* __restrict__ b_out, const unsigned short* __restrict__ w_sw,
    unsigned short* __restrict__ h, float* __restrict__ out, int s, int e) {
  __shared__ __align__(16) unsigned short Abuf[64][136];
  tile_body<LEAF>(x, mask, emb, b_in, b_out, w_sw, h, out, e,
                  s + blockIdx.x * 64, Abuf, threadIdx.x);
}

// Levels 2 (rows 9..72), 1 (rows 1..8), 0 (row 0) in one block.
// __syncthreads between tiles: the barrier's vmcnt(0) drain + L1 behavior
// (stores bypass/invalidate L1, lines not previously loaded this dispatch)
// makes same-block global h RAW safe.
__global__ __launch_bounds__(256) void tail_kernel(
    const int* __restrict__ x, const int* __restrict__ mask,
    const float* __restrict__ emb, const float* __restrict__ b_in,
    const float* __restrict__ b_out, const unsigned short* __restrict__ w_sw,
    unsigned short* __restrict__ h, float* __restrict__ out) {
  __shared__ __align__(16) unsigned short Abuf[64][136];
  tile_body<false>(x, mask, emb, b_in, b_out, w_sw, h, out, 73, 9, Abuf,
                   threadIdx.x);
  __syncthreads();
  tile_body<false>(x, mask, emb, b_in, b_out, w_sw, h, out, 9, 1, Abuf,
                   threadIdx.x);
  __syncthreads();
  tile_body<false>(x, mask, emb, b_in, b_out, w_sw, h, out, 1, 0, Abuf,
                   threadIdx.x);
}

extern "C" void kernel_launch(void* const* d_in, const int* in_sizes, int n_in,
                              void* d_out, int out_size, void* d_ws,
                              size_t ws_size, hipStream_t stream) {
  const int* x = (const int*)d_in[0];
  const int* mask = (const int*)d_in[1];
  // d_in[2] = children: implied (child rows of i are i*8+1..i*8+8)
  const float* emb = (const float*)d_in[3];
  const float* W_in = (const float*)d_in[4];
  const float* b_in = (const float*)d_in[5];
  const float* U = (const float*)d_in[6];
  const float* W_out = (const float*)d_in[7];
  const float* b_out = (const float*)d_in[8];
  float* out = (float*)d_out;

  // ws layout: h bf16 [NNODES*128 ushort] | swizzled weights [3*16384 ushort]
  unsigned short* h = (unsigned short*)d_ws;
  unsigned short* w_sw = h + (size_t)NNODES * 128;

  prep_weights<<<192, 256, 0, stream>>>(W_in, U, W_out, w_sw);

  // leaf level l=6: rows 37449..299592
  level_kernel<true><<<4096, 256, 0, stream>>>(x, mask, emb, b_in, b_out, w_sw,
                                               h, out, 37449, 299593);
  // l=5
  level_kernel<false><<<512, 256, 0, stream>>>(x, mask, emb, b_in, b_out, w_sw,
                                               h, out, 4681, 37449);
  // l=4
  level_kernel<false><<<64, 256, 0, stream>>>(x, mask, emb, b_in, b_out, w_sw,
                                              h, out, 585, 4681);
  // l=3
  level_kernel<false><<<8, 256, 0, stream>>>(x, mask, emb, b_in, b_out, w_sw,
                                             h, out, 73, 585);
  // l=2,1,0 merged
  tail_kernel<<<1, 256, 0, stream>>>(x, mask, emb, b_in, b_out, w_sw, h, out);
}